// Round 2
// baseline (9107.992 us; speedup 1.0000x reference)
//
#include <hip/hip_runtime.h>
#include <math.h>

#define BB 64
#define TT 64
#define INDIM 256
#define HH 512
#define NN 4096
#define MM 128
#define SS 16            // blocks per batch for the big sweeps
#define ROWS 256         // rows (n) per block = NN/SS
#define EPSF 1e-8f

__device__ __forceinline__ float sigmoidf_(float x){ return 1.f/(1.f+expf(-x)); }
__device__ __forceinline__ float softplusf_(float x){ return (x>20.f)? x : log1pf(expf(x)); }

// ---------------- Kernel A: mem update + r partials + mnorm ----------------
__global__ __launch_bounds__(256) void kA(
    const float* __restrict__ eG, const float* __restrict__ aG,
    const float* __restrict__ wrG, const float* __restrict__ wwG,
    float* __restrict__ mem, float* __restrict__ rpart, float* __restrict__ mnormG)
{
  const int b = blockIdx.y;
  const int n0 = blockIdx.x * ROWS;
  const int t = threadIdx.x;
  const int grp = t >> 5, lane = t & 31;
  const int m4 = lane * 4;
  const float4 e4 = *(const float4*)(eG + b*MM + m4);
  const float4 a4 = *(const float4*)(aG + b*MM + m4);
  float r0=0.f, r1=0.f, r2=0.f, r3=0.f;
  __shared__ float lr[8][128];
  const size_t base = ((size_t)b*NN)*MM;
  for (int rr=0; rr<32; ++rr){
    const int n = n0 + grp*32 + rr;
    const float wwv = wwG[b*NN+n];
    const float wrv = wrG[b*NN+n];
    float* mp = mem + base + (size_t)n*MM + m4;
    float4 mv = *(float4*)mp;
    mv.x = mv.x*(1.f - wwv*e4.x) + wwv*a4.x;
    mv.y = mv.y*(1.f - wwv*e4.y) + wwv*a4.y;
    mv.z = mv.z*(1.f - wwv*e4.z) + wwv*a4.z;
    mv.w = mv.w*(1.f - wwv*e4.w) + wwv*a4.w;
    *(float4*)mp = mv;
    r0 += wrv*mv.x; r1 += wrv*mv.y; r2 += wrv*mv.z; r3 += wrv*mv.w;
    float sq = mv.x*mv.x + mv.y*mv.y + mv.z*mv.z + mv.w*mv.w;
    #pragma unroll
    for (int msk=1; msk<32; msk<<=1) sq += __shfl_xor(sq, msk);
    if (lane==0) mnormG[b*NN+n] = sqrtf(sq);
  }
  lr[grp][m4+0]=r0; lr[grp][m4+1]=r1; lr[grp][m4+2]=r2; lr[grp][m4+3]=r3;
  __syncthreads();
  if (t < MM){
    float s=0.f;
    #pragma unroll
    for (int g=0; g<8; ++g) s += lr[g][t];
    rpart[((size_t)b*SS + blockIdx.x)*MM + t] = s;
  }
}

// ---------------- Kernel B: controller + heads (one block per batch) -------
__global__ __launch_bounds__(512) void kB(
    int tstep,
    const float* __restrict__ x, const float* __restrict__ Wx,
    const float* __restrict__ Wr, const float* __restrict__ bC,
    const float* __restrict__ rWk, const float* __restrict__ rbk,
    const float* __restrict__ rWbeta, const float* __restrict__ rWg,
    const float* __restrict__ rWs, const float* __restrict__ rWgam,
    const float* __restrict__ wWk, const float* __restrict__ wbk,
    const float* __restrict__ wWbeta, const float* __restrict__ wWg,
    const float* __restrict__ wWs, const float* __restrict__ wWgam,
    const float* __restrict__ wWe, const float* __restrict__ wWa,
    const float* __restrict__ rpart,
    float* __restrict__ hG, float* __restrict__ krG, float* __restrict__ kwG,
    float* __restrict__ eG, float* __restrict__ aG, float* __restrict__ scal)
{
  const int b = blockIdx.x, t = threadIdx.x;
  __shared__ float xs[INDIM], rs[MM], hs[HH], ks[2*MM], sd[14];
  if (t < INDIM) xs[t] = x[((size_t)b*TT + tstep)*INDIM + t];
  if (t < MM){
    float s=0.f;
    #pragma unroll
    for (int i=0;i<SS;++i) s += rpart[((size_t)b*SS+i)*MM + t];
    rs[t]=s;
  }
  __syncthreads();
  {
    float acc = bC[t];
    #pragma unroll 4
    for (int i=0;i<INDIM;++i) acc += xs[i]*Wx[(size_t)i*HH + t];
    #pragma unroll 4
    for (int m=0;m<MM;++m) acc += rs[m]*Wr[(size_t)m*HH + t];
    float hv = tanhf(acc);
    hs[t]=hv; hG[(size_t)b*HH+t]=hv;
  }
  __syncthreads();
  {
    const int q = t >> 7, m = t & 127;
    const float* W = (q==0)? rWk : (q==1)? wWk : (q==2)? wWe : wWa;
    float acc = (q==0)? rbk[m] : (q==1)? wbk[m] : 0.f;
    #pragma unroll 4
    for (int j=0;j<HH;++j) acc += hs[j]*W[(size_t)j*MM + m];
    if (q==0){ float v=tanhf(acc); ks[m]=v;    krG[b*MM+m]=v; }
    else if (q==1){ float v=tanhf(acc); ks[MM+m]=v; kwG[b*MM+m]=v; }
    else if (q==2){ eG[b*MM+m]=sigmoidf_(acc); }
    else          { aG[b*MM+m]=tanhf(acc); }
  }
  __syncthreads();
  {
    const int wv = t>>6, ln = t&63;
    for (int jj=wv; jj<14; jj+=8){
      float acc=0.f;
      if (jj==6 || jj==13){
        const int o = (jj==6)? 0 : MM;
        const float v1=ks[o+ln], v2=ks[o+64+ln];
        acc = v1*v1 + v2*v2;
      } else {
        const int j2 = (jj<7)? jj : jj-7;
        const bool rd = (jj<7);
        const float* W; int C, c;
        switch (j2){
          case 0: W = rd? rWbeta : wWbeta; C=1; c=0; break;
          case 1: W = rd? rWg   : wWg;    C=1; c=0; break;
          case 2: W = rd? rWgam : wWgam;  C=1; c=0; break;
          default: W = rd? rWs  : wWs;    C=3; c=j2-3; break;
        }
        for (int j=ln; j<HH; j+=64) acc += hs[j]*W[j*C + c];
      }
      #pragma unroll
      for (int msk=1; msk<64; msk<<=1) acc += __shfl_xor(acc, msk);
      if (ln==0) sd[jj]=acc;
    }
  }
  __syncthreads();
  if (t==0){
    float* sc = scal + b*16;
    sc[0] = softplusf_(sd[0]);
    sc[1] = sigmoidf_(sd[1]);
    sc[2] = 1.f + softplusf_(sd[2]);
    {
      float mx = fmaxf(sd[3], fmaxf(sd[4], sd[5]));
      float e0=expf(sd[3]-mx), e1=expf(sd[4]-mx), e2=expf(sd[5]-mx);
      float inv=1.f/(e0+e1+e2);
      sc[3]=e0*inv; sc[4]=e1*inv; sc[5]=e2*inv;
    }
    sc[6] = sqrtf(sd[6]);
    sc[8]  = softplusf_(sd[7]);
    sc[9]  = sigmoidf_(sd[8]);
    sc[10] = 1.f + softplusf_(sd[9]);
    {
      float mx = fmaxf(sd[10], fmaxf(sd[11], sd[12]));
      float e0=expf(sd[10]-mx), e1=expf(sd[11]-mx), e2=expf(sd[12]-mx);
      float inv=1.f/(e0+e1+e2);
      sc[11]=e0*inv; sc[12]=e1*inv; sc[13]=e2*inv;
    }
    sc[14] = sqrtf(sd[13]);
  }
}

// ---------------- Kernel C: content dots for both heads --------------------
__global__ __launch_bounds__(256) void kC(
    const float* __restrict__ mem,
    const float* __restrict__ krG, const float* __restrict__ kwG,
    float* __restrict__ dotrG, float* __restrict__ dotwG)
{
  const int b = blockIdx.y;
  const int n0 = blockIdx.x * ROWS;
  const int t = threadIdx.x, grp=t>>5, lane=t&31, m4=lane*4;
  const float4 kr = *(const float4*)(krG + b*MM + m4);
  const float4 kw = *(const float4*)(kwG + b*MM + m4);
  const size_t base = ((size_t)b*NN)*MM;
  for (int rr=0; rr<32; ++rr){
    const int n = n0 + grp*32 + rr;
    const float4 mv = *(const float4*)(mem + base + (size_t)n*MM + m4);
    float dr = mv.x*kr.x + mv.y*kr.y + mv.z*kr.z + mv.w*kr.w;
    float dw = mv.x*kw.x + mv.y*kw.y + mv.z*kw.z + mv.w*kw.w;
    #pragma unroll
    for (int msk=1; msk<32; msk<<=1){
      dr += __shfl_xor(dr, msk);
      dw += __shfl_xor(dw, msk);
    }
    if (lane==0){ dotrG[b*NN+n]=dr; dotwG[b*NN+n]=dw; }
  }
}

// ---------------- Kernel D: softmax + interpolate + shift + sharpen --------
__device__ __forceinline__ float blockSum256(float v, volatile float* sc){
  #pragma unroll
  for (int m=1;m<64;m<<=1) v += __shfl_xor(v,m);
  __syncthreads();
  if ((threadIdx.x&63)==0) sc[threadIdx.x>>6]=v;
  __syncthreads();
  return sc[0]+sc[1]+sc[2]+sc[3];
}
__device__ __forceinline__ float blockMax256(float v, volatile float* sc){
  #pragma unroll
  for (int m=1;m<64;m<<=1) v = fmaxf(v, __shfl_xor(v,m));
  __syncthreads();
  if ((threadIdx.x&63)==0) sc[threadIdx.x>>6]=v;
  __syncthreads();
  return fmaxf(fmaxf(sc[0],sc[1]), fmaxf(sc[2],sc[3]));
}

__global__ __launch_bounds__(256) void kD(
    const float* __restrict__ dotrG, const float* __restrict__ dotwG,
    const float* __restrict__ mnormG, const float* __restrict__ scal,
    float* __restrict__ wrG, float* __restrict__ wwG)
{
  const int b = blockIdx.x, head = blockIdx.y, t = threadIdx.x;
  __shared__ float wg[NN];
  __shared__ float sc[4];
  const float* dot = head? dotwG : dotrG;
  float* wv = head? wwG : wrG;
  const float* sb = scal + b*16 + head*8;
  const float beta=sb[0], g=sb[1], gamma=sb[2];
  const float s0=sb[3], s1=sb[4], s2=sb[5], knorm=sb[6];
  float sim[16]; float mx = -1e30f;
  #pragma unroll
  for (int i=0;i<16;++i){
    const int n = i*256 + t;
    const float d  = dot[(size_t)b*NN+n];
    const float mn = mnormG[(size_t)b*NN+n];
    sim[i] = beta*d/(mn*knorm + EPSF);
    mx = fmaxf(mx, sim[i]);
  }
  mx = blockMax256(mx, sc);
  float sum=0.f;
  #pragma unroll
  for (int i=0;i<16;++i){ sim[i]=expf(sim[i]-mx); sum += sim[i]; }
  sum = blockSum256(sum, sc);
  const float inv = 1.f/sum;
  #pragma unroll
  for (int i=0;i<16;++i){
    const int n = i*256 + t;
    wg[n] = g*sim[i]*inv + (1.f-g)*wv[(size_t)b*NN+n];
  }
  __syncthreads();
  float wp[16]; float ps=0.f;
  #pragma unroll
  for (int i=0;i<16;++i){
    const int n = i*256 + t;
    const float wt = s0*wg[(n+1)&(NN-1)] + s1*wg[n] + s2*wg[(n-1)&(NN-1)];
    wp[i] = powf(wt + EPSF, gamma);
    ps += wp[i];
  }
  ps = blockSum256(ps, sc);
  const float ip = 1.f/ps;
  #pragma unroll
  for (int i=0;i<16;++i){
    const int n = i*256 + t;
    wv[(size_t)b*NN+n] = wp[i]*ip;
  }
}

// ---------------- init / output -------------------------------------------
__global__ void kInit(float* wr, float* ww, float* h, float* e, float* a){
  const int i = blockIdx.x*blockDim.x + threadIdx.x;
  if (i < BB*NN){ const float v = (i==0)? 1.f : 0.f; wr[i]=v; ww[i]=v; }
  if (i < BB*HH) h[i]=0.f;
  if (i < BB*MM){ e[i]=0.5f; a[i]=0.f; }
}
__global__ void kOut(const float* __restrict__ h, float* __restrict__ out){
  const int i = blockIdx.x*blockDim.x + threadIdx.x;
  if (i < BB*HH) out[i]=h[i];
}

extern "C" void kernel_launch(void* const* d_in, const int* in_sizes, int n_in,
                              void* d_out, int out_size, void* d_ws, size_t ws_size,
                              hipStream_t stream)
{
  const float* x     = (const float*)d_in[0];
  const float* mem0  = (const float*)d_in[1];
  const float* Wx    = (const float*)d_in[2];
  const float* Wr    = (const float*)d_in[3];
  const float* bC    = (const float*)d_in[4];
  const float* rWk   = (const float*)d_in[5];
  const float* rbk   = (const float*)d_in[6];
  const float* rWbeta= (const float*)d_in[7];
  const float* rWg   = (const float*)d_in[8];
  const float* rWs   = (const float*)d_in[9];
  const float* rWgam = (const float*)d_in[10];
  const float* wWk   = (const float*)d_in[11];
  const float* wbk   = (const float*)d_in[12];
  const float* wWbeta= (const float*)d_in[13];
  const float* wWg   = (const float*)d_in[14];
  const float* wWs   = (const float*)d_in[15];
  const float* wWgam = (const float*)d_in[16];
  const float* wWe   = (const float*)d_in[17];
  const float* wWa   = (const float*)d_in[18];

  float* ws = (float*)d_ws;
  size_t o = 0;
  float* mem   = ws + o; o += (size_t)BB*NN*MM;
  float* wr    = ws + o; o += (size_t)BB*NN;
  float* ww    = ws + o; o += (size_t)BB*NN;
  float* h     = ws + o; o += (size_t)BB*HH;
  float* rpart = ws + o; o += (size_t)BB*SS*MM;
  float* e     = ws + o; o += (size_t)BB*MM;
  float* a     = ws + o; o += (size_t)BB*MM;
  float* kr    = ws + o; o += (size_t)BB*MM;
  float* kw    = ws + o; o += (size_t)BB*MM;
  float* mnorm = ws + o; o += (size_t)BB*NN;
  float* dotr  = ws + o; o += (size_t)BB*NN;
  float* dotw  = ws + o; o += (size_t)BB*NN;
  float* scal  = ws + o; o += (size_t)BB*16;

  (void)hipMemcpyAsync(mem, mem0, (size_t)BB*NN*MM*sizeof(float),
                       hipMemcpyDeviceToDevice, stream);
  kInit<<<(BB*NN+255)/256, 256, 0, stream>>>(wr, ww, h, e, a);

  for (int t=0; t<TT; ++t){
    kA<<<dim3(SS,BB), 256, 0, stream>>>(e, a, wr, ww, mem, rpart, mnorm);
    kB<<<BB, 512, 0, stream>>>(t, x, Wx, Wr, bC,
                               rWk, rbk, rWbeta, rWg, rWs, rWgam,
                               wWk, wbk, wWbeta, wWg, wWs, wWgam, wWe, wWa,
                               rpart, h, kr, kw, e, a, scal);
    if (t < TT-1){
      kC<<<dim3(SS,BB), 256, 0, stream>>>(mem, kr, kw, dotr, dotw);
      kD<<<dim3(BB,2), 256, 0, stream>>>(dotr, dotw, mnorm, scal, wr, ww);
    }
  }
  kOut<<<(BB*HH+255)/256, 256, 0, stream>>>(h, (float*)d_out);
}

// Round 3
// 5216.169 us; speedup vs baseline: 1.7461x; 1.7461x over previous
//
#include <hip/hip_runtime.h>
#include <math.h>

#define BB 64
#define TT 64
#define INDIM 256
#define HH 512
#define NN 4096
#define MM 128
#define SS 16            // blocks per batch for the big sweeps
#define ROWS 256         // rows (n) per block = NN/SS
#define EPSF 1e-8f

__device__ __forceinline__ float sigmoidf_(float x){ return 1.f/(1.f+expf(-x)); }
__device__ __forceinline__ float softplusf_(float x){ return (x>20.f)? x : log1pf(expf(x)); }

// bf16 pair helpers: u32 holds elem0 in low 16, elem1 in high 16.
__device__ __forceinline__ void unpack2(unsigned u, float& lo, float& hi){
  lo = __uint_as_float(u << 16);
  hi = __uint_as_float(u & 0xffff0000u);
}
__device__ __forceinline__ unsigned pack2(float a, float b){
  unsigned ua = __float_as_uint(a), ub = __float_as_uint(b);
  ua += 0x7fffu + ((ua >> 16) & 1u);
  ub += 0x7fffu + ((ub >> 16) & 1u);
  return (ua >> 16) | (ub & 0xffff0000u);
}

// ---------------- kCvt: fp32 mem0 -> bf16 mem ------------------------------
__global__ __launch_bounds__(256) void kCvt(const float* __restrict__ src,
                                            uint4* __restrict__ dst){
  const size_t i = (size_t)blockIdx.x*blockDim.x + threadIdx.x; // one uint4 = 8 elems
  const float4 f0 = *(const float4*)(src + i*8);
  const float4 f1 = *(const float4*)(src + i*8 + 4);
  uint4 q;
  q.x = pack2(f0.x, f0.y); q.y = pack2(f0.z, f0.w);
  q.z = pack2(f1.x, f1.y); q.w = pack2(f1.z, f1.w);
  dst[i] = q;
}

// ---------------- kPre: xwx[b,t,h] = bC[h] + x[b,t,:]@Wx -------------------
__global__ __launch_bounds__(512) void kPre(const float* __restrict__ x,
                                            const float* __restrict__ Wx,
                                            const float* __restrict__ bC,
                                            float* __restrict__ xwx){
  const int bt = blockIdx.x, t = threadIdx.x;
  __shared__ float xs[INDIM];
  if (t < INDIM) xs[t] = x[(size_t)bt*INDIM + t];
  __syncthreads();
  float acc = bC[t];
  #pragma unroll 4
  for (int i=0;i<INDIM;++i) acc += xs[i]*Wx[(size_t)i*HH + t];
  xwx[(size_t)bt*HH + t] = acc;
}

// ---------------- Kernel A: mem update + r partials + mnorm ----------------
// 256 thr = 16 groups of 16 lanes; row = 128 bf16 = 16 lanes x 16B.
__global__ __launch_bounds__(256) void kA(
    const float* __restrict__ eG, const float* __restrict__ aG,
    const float* __restrict__ wrG, const float* __restrict__ wwG,
    uint4* __restrict__ mem, float* __restrict__ rpart, float* __restrict__ mnormG)
{
  const int b = blockIdx.y;
  const int n0 = blockIdx.x * ROWS;
  const int t = threadIdx.x;
  const int grp = t >> 4, lane = t & 15;
  const int m0 = lane * 8;
  float ev[8], av[8];
  {
    const float4 e0 = *(const float4*)(eG + b*MM + m0);
    const float4 e1 = *(const float4*)(eG + b*MM + m0 + 4);
    const float4 a0 = *(const float4*)(aG + b*MM + m0);
    const float4 a1 = *(const float4*)(aG + b*MM + m0 + 4);
    ev[0]=e0.x; ev[1]=e0.y; ev[2]=e0.z; ev[3]=e0.w;
    ev[4]=e1.x; ev[5]=e1.y; ev[6]=e1.z; ev[7]=e1.w;
    av[0]=a0.x; av[1]=a0.y; av[2]=a0.z; av[3]=a0.w;
    av[4]=a1.x; av[5]=a1.y; av[6]=a1.z; av[7]=a1.w;
  }
  float racc[8];
  #pragma unroll
  for (int j=0;j<8;++j) racc[j]=0.f;
  __shared__ float lr[16][128];
  const size_t rowbase = ((size_t)b*NN + n0) * (MM/8); // in uint4 units
  for (int rr=0; rr<16; ++rr){
    const int n = n0 + rr*16 + grp;
    const float wwv = wwG[b*NN+n];
    const float wrv = wrG[b*NN+n];
    uint4* mp = mem + rowbase + (size_t)(rr*16+grp)*(MM/8) + lane;
    uint4 q = *mp;
    float v[8];
    unpack2(q.x, v[0], v[1]); unpack2(q.y, v[2], v[3]);
    unpack2(q.z, v[4], v[5]); unpack2(q.w, v[6], v[7]);
    float sq = 0.f;
    #pragma unroll
    for (int j=0;j<8;++j){
      v[j] = v[j]*(1.f - wwv*ev[j]) + wwv*av[j];
      racc[j] += wrv*v[j];
      sq += v[j]*v[j];
    }
    q.x = pack2(v[0],v[1]); q.y = pack2(v[2],v[3]);
    q.z = pack2(v[4],v[5]); q.w = pack2(v[6],v[7]);
    *mp = q;
    #pragma unroll
    for (int msk=1; msk<16; msk<<=1) sq += __shfl_xor(sq, msk);
    if (lane==0) mnormG[b*NN+n] = sqrtf(sq);
  }
  #pragma unroll
  for (int j=0;j<8;++j) lr[grp][m0+j] = racc[j];
  __syncthreads();
  if (t < MM){
    float s=0.f;
    #pragma unroll
    for (int g=0; g<16; ++g) s += lr[g][t];
    rpart[((size_t)b*SS + blockIdx.x)*MM + t] = s;
  }
}

// ---------------- Kernel B: controller + heads (one block per batch) -------
__global__ __launch_bounds__(1024) void kB(
    const float* __restrict__ xwx, int tstep,
    const float* __restrict__ Wr,
    const float* __restrict__ rWk, const float* __restrict__ rbk,
    const float* __restrict__ rWbeta, const float* __restrict__ rWg,
    const float* __restrict__ rWs, const float* __restrict__ rWgam,
    const float* __restrict__ wWk, const float* __restrict__ wbk,
    const float* __restrict__ wWbeta, const float* __restrict__ wWg,
    const float* __restrict__ wWs, const float* __restrict__ wWgam,
    const float* __restrict__ wWe, const float* __restrict__ wWa,
    const float* __restrict__ rpart,
    float* __restrict__ hG, float* __restrict__ krG, float* __restrict__ kwG,
    float* __restrict__ eG, float* __restrict__ aG, float* __restrict__ scal)
{
  const int b = blockIdx.x, t = threadIdx.x;
  __shared__ float rs[MM], hs[HH], ks[2*MM], sd[14], hd[8][128];
  if (t < MM){
    float s=0.f;
    #pragma unroll
    for (int i=0;i<SS;++i) s += rpart[((size_t)b*SS+i)*MM + t];
    rs[t]=s;
  }
  __syncthreads();
  if (t < HH){
    float acc = xwx[((size_t)b*TT + tstep)*HH + t];
    #pragma unroll 4
    for (int m=0;m<MM;++m) acc += rs[m]*Wr[(size_t)m*HH + t];
    float hv = tanhf(acc);
    hs[t]=hv; hG[(size_t)b*HH+t]=hv;
  }
  __syncthreads();
  {
    const int q = t >> 7, m = t & 127;
    const int head = q & 3, jh = q >> 2;
    const float* W = (head==0)? rWk : (head==1)? wWk : (head==2)? wWe : wWa;
    float acc = 0.f;
    const int j0 = jh*256;
    #pragma unroll 4
    for (int j=j0; j<j0+256; ++j) acc += hs[j]*W[(size_t)j*MM + m];
    hd[q][m] = acc;
  }
  __syncthreads();
  if (t < 512){
    const int q = t >> 7, m = t & 127;
    float acc = hd[q][m] + hd[q+4][m];
    if (q==0){ float v=tanhf(acc + rbk[m]); ks[m]=v;    krG[b*MM+m]=v; }
    else if (q==1){ float v=tanhf(acc + wbk[m]); ks[MM+m]=v; kwG[b*MM+m]=v; }
    else if (q==2){ eG[b*MM+m]=sigmoidf_(acc); }
    else          { aG[b*MM+m]=tanhf(acc); }
  }
  __syncthreads();
  {
    const int wv = t>>6, ln = t&63;
    if (wv < 14){
      const int jj = wv;
      float acc=0.f;
      if (jj==6 || jj==13){
        const int o = (jj==6)? 0 : MM;
        const float v1=ks[o+ln], v2=ks[o+64+ln];
        acc = v1*v1 + v2*v2;
      } else {
        const int j2 = (jj<7)? jj : jj-7;
        const bool rd = (jj<7);
        const float* W; int C, c;
        switch (j2){
          case 0: W = rd? rWbeta : wWbeta; C=1; c=0; break;
          case 1: W = rd? rWg   : wWg;    C=1; c=0; break;
          case 2: W = rd? rWgam : wWgam;  C=1; c=0; break;
          default: W = rd? rWs  : wWs;    C=3; c=j2-3; break;
        }
        for (int j=ln; j<HH; j+=64) acc += hs[j]*W[j*C + c];
      }
      #pragma unroll
      for (int msk=1; msk<64; msk<<=1) acc += __shfl_xor(acc, msk);
      if (ln==0) sd[jj]=acc;
    }
  }
  __syncthreads();
  if (t==0){
    float* sc = scal + b*16;
    sc[0] = softplusf_(sd[0]);
    sc[1] = sigmoidf_(sd[1]);
    sc[2] = 1.f + softplusf_(sd[2]);
    {
      float mx = fmaxf(sd[3], fmaxf(sd[4], sd[5]));
      float e0=expf(sd[3]-mx), e1=expf(sd[4]-mx), e2=expf(sd[5]-mx);
      float inv=1.f/(e0+e1+e2);
      sc[3]=e0*inv; sc[4]=e1*inv; sc[5]=e2*inv;
    }
    sc[6] = sqrtf(sd[6]);
    sc[8]  = softplusf_(sd[7]);
    sc[9]  = sigmoidf_(sd[8]);
    sc[10] = 1.f + softplusf_(sd[9]);
    {
      float mx = fmaxf(sd[10], fmaxf(sd[11], sd[12]));
      float e0=expf(sd[10]-mx), e1=expf(sd[11]-mx), e2=expf(sd[12]-mx);
      float inv=1.f/(e0+e1+e2);
      sc[11]=e0*inv; sc[12]=e1*inv; sc[13]=e2*inv;
    }
    sc[14] = sqrtf(sd[13]);
  }
}

// ---------------- Kernel C: content dots for both heads --------------------
__global__ __launch_bounds__(256) void kC(
    const uint4* __restrict__ mem,
    const float* __restrict__ krG, const float* __restrict__ kwG,
    float* __restrict__ dotrG, float* __restrict__ dotwG)
{
  const int b = blockIdx.y;
  const int n0 = blockIdx.x * ROWS;
  const int t = threadIdx.x, grp=t>>4, lane=t&15;
  const int m0 = lane*8;
  float krv[8], kwv[8];
  {
    const float4 k0 = *(const float4*)(krG + b*MM + m0);
    const float4 k1 = *(const float4*)(krG + b*MM + m0 + 4);
    const float4 w0 = *(const float4*)(kwG + b*MM + m0);
    const float4 w1 = *(const float4*)(kwG + b*MM + m0 + 4);
    krv[0]=k0.x; krv[1]=k0.y; krv[2]=k0.z; krv[3]=k0.w;
    krv[4]=k1.x; krv[5]=k1.y; krv[6]=k1.z; krv[7]=k1.w;
    kwv[0]=w0.x; kwv[1]=w0.y; kwv[2]=w0.z; kwv[3]=w0.w;
    kwv[4]=w1.x; kwv[5]=w1.y; kwv[6]=w1.z; kwv[7]=w1.w;
  }
  const size_t rowbase = ((size_t)b*NN + n0) * (MM/8);
  for (int rr=0; rr<16; ++rr){
    const int n = n0 + rr*16 + grp;
    const uint4 q = mem[rowbase + (size_t)(rr*16+grp)*(MM/8) + lane];
    float v[8];
    unpack2(q.x, v[0], v[1]); unpack2(q.y, v[2], v[3]);
    unpack2(q.z, v[4], v[5]); unpack2(q.w, v[6], v[7]);
    float dr=0.f, dw=0.f;
    #pragma unroll
    for (int j=0;j<8;++j){ dr += v[j]*krv[j]; dw += v[j]*kwv[j]; }
    #pragma unroll
    for (int msk=1; msk<16; msk<<=1){
      dr += __shfl_xor(dr, msk);
      dw += __shfl_xor(dw, msk);
    }
    if (lane==0){ dotrG[b*NN+n]=dr; dotwG[b*NN+n]=dw; }
  }
}

// ---------------- Kernel D: softmax + interpolate + shift + sharpen --------
__device__ __forceinline__ float blockSum256(float v, volatile float* sc){
  #pragma unroll
  for (int m=1;m<64;m<<=1) v += __shfl_xor(v,m);
  __syncthreads();
  if ((threadIdx.x&63)==0) sc[threadIdx.x>>6]=v;
  __syncthreads();
  return sc[0]+sc[1]+sc[2]+sc[3];
}
__device__ __forceinline__ float blockMax256(float v, volatile float* sc){
  #pragma unroll
  for (int m=1;m<64;m<<=1) v = fmaxf(v, __shfl_xor(v,m));
  __syncthreads();
  if ((threadIdx.x&63)==0) sc[threadIdx.x>>6]=v;
  __syncthreads();
  return fmaxf(fmaxf(sc[0],sc[1]), fmaxf(sc[2],sc[3]));
}

__global__ __launch_bounds__(256) void kD(
    const float* __restrict__ dotrG, const float* __restrict__ dotwG,
    const float* __restrict__ mnormG, const float* __restrict__ scal,
    float* __restrict__ wrG, float* __restrict__ wwG)
{
  const int b = blockIdx.x, head = blockIdx.y, t = threadIdx.x;
  __shared__ float wg[NN];
  __shared__ float sc[4];
  const float* dot = head? dotwG : dotrG;
  float* wv = head? wwG : wrG;
  const float* sb = scal + b*16 + head*8;
  const float beta=sb[0], g=sb[1], gamma=sb[2];
  const float s0=sb[3], s1=sb[4], s2=sb[5], knorm=sb[6];
  float sim[16]; float mx = -1e30f;
  #pragma unroll
  for (int i=0;i<16;++i){
    const int n = i*256 + t;
    const float d  = dot[(size_t)b*NN+n];
    const float mn = mnormG[(size_t)b*NN+n];
    sim[i] = beta*d/(mn*knorm + EPSF);
    mx = fmaxf(mx, sim[i]);
  }
  mx = blockMax256(mx, sc);
  float sum=0.f;
  #pragma unroll
  for (int i=0;i<16;++i){ sim[i]=expf(sim[i]-mx); sum += sim[i]; }
  sum = blockSum256(sum, sc);
  const float inv = 1.f/sum;
  #pragma unroll
  for (int i=0;i<16;++i){
    const int n = i*256 + t;
    wg[n] = g*sim[i]*inv + (1.f-g)*wv[(size_t)b*NN+n];
  }
  __syncthreads();
  float wp[16]; float ps=0.f;
  #pragma unroll
  for (int i=0;i<16;++i){
    const int n = i*256 + t;
    const float wt = s0*wg[(n+1)&(NN-1)] + s1*wg[n] + s2*wg[(n-1)&(NN-1)];
    wp[i] = powf(wt + EPSF, gamma);
    ps += wp[i];
  }
  ps = blockSum256(ps, sc);
  const float ip = 1.f/ps;
  #pragma unroll
  for (int i=0;i<16;++i){
    const int n = i*256 + t;
    wv[(size_t)b*NN+n] = wp[i]*ip;
  }
}

// ---------------- init / output -------------------------------------------
__global__ void kInit(float* wr, float* ww, float* h, float* e, float* a){
  const int i = blockIdx.x*blockDim.x + threadIdx.x;
  if (i < BB*NN){ const float v = (i==0)? 1.f : 0.f; wr[i]=v; ww[i]=v; }
  if (i < BB*HH) h[i]=0.f;
  if (i < BB*MM){ e[i]=0.5f; a[i]=0.f; }
}
__global__ void kOut(const float* __restrict__ h, float* __restrict__ out){
  const int i = blockIdx.x*blockDim.x + threadIdx.x;
  if (i < BB*HH) out[i]=h[i];
}

extern "C" void kernel_launch(void* const* d_in, const int* in_sizes, int n_in,
                              void* d_out, int out_size, void* d_ws, size_t ws_size,
                              hipStream_t stream)
{
  const float* x     = (const float*)d_in[0];
  const float* mem0  = (const float*)d_in[1];
  const float* Wx    = (const float*)d_in[2];
  const float* Wr    = (const float*)d_in[3];
  const float* bC    = (const float*)d_in[4];
  const float* rWk   = (const float*)d_in[5];
  const float* rbk   = (const float*)d_in[6];
  const float* rWbeta= (const float*)d_in[7];
  const float* rWg   = (const float*)d_in[8];
  const float* rWs   = (const float*)d_in[9];
  const float* rWgam = (const float*)d_in[10];
  const float* wWk   = (const float*)d_in[11];
  const float* wbk   = (const float*)d_in[12];
  const float* wWbeta= (const float*)d_in[13];
  const float* wWg   = (const float*)d_in[14];
  const float* wWs   = (const float*)d_in[15];
  const float* wWgam = (const float*)d_in[16];
  const float* wWe   = (const float*)d_in[17];
  const float* wWa   = (const float*)d_in[18];

  float* ws = (float*)d_ws;
  size_t o = 0;
  uint4* mem   = (uint4*)(ws + o); o += (size_t)BB*NN*MM/2;  // bf16 = half the floats
  float* wr    = ws + o; o += (size_t)BB*NN;
  float* ww    = ws + o; o += (size_t)BB*NN;
  float* h     = ws + o; o += (size_t)BB*HH;
  float* rpart = ws + o; o += (size_t)BB*SS*MM;
  float* e     = ws + o; o += (size_t)BB*MM;
  float* a     = ws + o; o += (size_t)BB*MM;
  float* kr    = ws + o; o += (size_t)BB*MM;
  float* kw    = ws + o; o += (size_t)BB*MM;
  float* mnorm = ws + o; o += (size_t)BB*NN;
  float* dotr  = ws + o; o += (size_t)BB*NN;
  float* dotw  = ws + o; o += (size_t)BB*NN;
  float* scal  = ws + o; o += (size_t)BB*16;
  float* xwx   = ws + o; o += (size_t)BB*TT*HH;

  kCvt<<<(BB*NN*MM/8)/256, 256, 0, stream>>>(mem0, mem);
  kInit<<<(BB*NN+255)/256, 256, 0, stream>>>(wr, ww, h, e, a);
  kPre<<<BB*TT, 512, 0, stream>>>(x, Wx, bC, xwx);

  for (int t=0; t<TT; ++t){
    kA<<<dim3(SS,BB), 256, 0, stream>>>(e, a, wr, ww, mem, rpart, mnorm);
    kB<<<BB, 1024, 0, stream>>>(xwx, t, Wr,
                               rWk, rbk, rWbeta, rWg, rWs, rWgam,
                               wWk, wbk, wWbeta, wWg, wWs, wWgam, wWe, wWa,
                               rpart, h, kr, kw, e, a, scal);
    if (t < TT-1){
      kC<<<dim3(SS,BB), 256, 0, stream>>>(mem, kr, kw, dotr, dotw);
      kD<<<dim3(BB,2), 256, 0, stream>>>(dotr, dotw, mnorm, scal, wr, ww);
    }
  }
  kOut<<<(BB*HH+255)/256, 256, 0, stream>>>(h, (float*)d_out);
}

// Round 4
// 5053.812 us; speedup vs baseline: 1.8022x; 1.0321x over previous
//
#include <hip/hip_runtime.h>
#include <hip/hip_bf16.h>
#include <math.h>

#define BB 64
#define TT 64
#define INDIM 256
#define HH 512
#define NN 4096
#define MM 128
#define SS 32            // blocks per batch for the big sweeps
#define ROWS 128         // rows (n) per block = NN/SS
#define EPSF 1e-8f

__device__ __forceinline__ float sigmoidf_(float x){ return 1.f/(1.f+expf(-x)); }
__device__ __forceinline__ float softplusf_(float x){ return (x>20.f)? x : log1pf(expf(x)); }

// bf16 pair helpers: u32 holds elem0 in low 16, elem1 in high 16.
__device__ __forceinline__ void unpack2(unsigned u, float& lo, float& hi){
  lo = __uint_as_float(u << 16);
  hi = __uint_as_float(u & 0xffff0000u);
}
__device__ __forceinline__ unsigned packrn(float a, float b){
  __hip_bfloat162 p = __float22bfloat162_rn(make_float2(a,b));
  return *reinterpret_cast<unsigned*>(&p);
}

// ---------------- kCvt: fp32 mem0 -> bf16 mem ------------------------------
__global__ __launch_bounds__(256) void kCvt(const float* __restrict__ src,
                                            uint4* __restrict__ dst){
  const size_t i = (size_t)blockIdx.x*blockDim.x + threadIdx.x; // one uint4 = 8 elems
  const float4 f0 = *(const float4*)(src + i*8);
  const float4 f1 = *(const float4*)(src + i*8 + 4);
  uint4 q;
  q.x = packrn(f0.x, f0.y); q.y = packrn(f0.z, f0.w);
  q.z = packrn(f1.x, f1.y); q.w = packrn(f1.z, f1.w);
  dst[i] = q;
}

// ---------------- kPre: xwx[b,t,h] = bC[h] + x[b,t,:]@Wx -------------------
__global__ __launch_bounds__(512) void kPre(const float* __restrict__ x,
                                            const float* __restrict__ Wx,
                                            const float* __restrict__ bC,
                                            float* __restrict__ xwx){
  const int bt = blockIdx.x, t = threadIdx.x;
  __shared__ float xs[INDIM];
  if (t < INDIM) xs[t] = x[(size_t)bt*INDIM + t];
  __syncthreads();
  float acc = bC[t];
  #pragma unroll 4
  for (int i=0;i<INDIM;++i) acc += xs[i]*Wx[(size_t)i*HH + t];
  xwx[(size_t)bt*HH + t] = acc;
}

// ---------------- Kernel A: mem update + r partials + mnorm ----------------
// 256 thr = 16 groups of 16 lanes; row = 128 bf16 = 16 lanes x 16B.
__global__ __launch_bounds__(256) void kA(
    const float* __restrict__ eG, const float* __restrict__ aG,
    const float* __restrict__ wrG, const float* __restrict__ wwG,
    uint4* __restrict__ mem, float* __restrict__ rpart, float* __restrict__ mnormG)
{
  const int b = blockIdx.y;
  const int n0 = blockIdx.x * ROWS;
  const int t = threadIdx.x;
  const int grp = t >> 4, lane = t & 15;
  const int m0 = lane * 8;
  float ev[8], av[8];
  {
    const float4 e0 = *(const float4*)(eG + b*MM + m0);
    const float4 e1 = *(const float4*)(eG + b*MM + m0 + 4);
    const float4 a0 = *(const float4*)(aG + b*MM + m0);
    const float4 a1 = *(const float4*)(aG + b*MM + m0 + 4);
    ev[0]=e0.x; ev[1]=e0.y; ev[2]=e0.z; ev[3]=e0.w;
    ev[4]=e1.x; ev[5]=e1.y; ev[6]=e1.z; ev[7]=e1.w;
    av[0]=a0.x; av[1]=a0.y; av[2]=a0.z; av[3]=a0.w;
    av[4]=a1.x; av[5]=a1.y; av[6]=a1.z; av[7]=a1.w;
  }
  // preload the 8 per-row scalars for this lane-group
  float wwv[8], wrv[8];
  #pragma unroll
  for (int rr=0; rr<8; ++rr){
    const int n = n0 + rr*16 + grp;
    wwv[rr] = wwG[b*NN+n];
    wrv[rr] = wrG[b*NN+n];
  }
  float racc[8];
  #pragma unroll
  for (int j=0;j<8;++j) racc[j]=0.f;
  __shared__ float lr[16][128];
  const size_t base4 = ((size_t)b*NN + n0)*(MM/8) + (size_t)grp*(MM/8) + lane;
  uint4 q = mem[base4];
  #pragma unroll
  for (int rr=0; rr<8; ++rr){
    uint4 qn;
    if (rr<7) qn = mem[base4 + (size_t)(rr+1)*16*(MM/8)];   // prefetch next row-group
    const int n = n0 + rr*16 + grp;
    float v[8];
    unpack2(q.x, v[0], v[1]); unpack2(q.y, v[2], v[3]);
    unpack2(q.z, v[4], v[5]); unpack2(q.w, v[6], v[7]);
    float sq = 0.f;
    const float w = wwv[rr], wr_ = wrv[rr];
    #pragma unroll
    for (int j=0;j<8;++j){
      v[j] = v[j]*(1.f - w*ev[j]) + w*av[j];
      racc[j] += wr_*v[j];
      sq += v[j]*v[j];
    }
    uint4 q2;
    q2.x = packrn(v[0],v[1]); q2.y = packrn(v[2],v[3]);
    q2.z = packrn(v[4],v[5]); q2.w = packrn(v[6],v[7]);
    mem[base4 + (size_t)rr*16*(MM/8)] = q2;
    #pragma unroll
    for (int msk=1; msk<16; msk<<=1) sq += __shfl_xor(sq, msk);
    if (lane==0) mnormG[b*NN+n] = sqrtf(sq);
    q = qn;
  }
  #pragma unroll
  for (int j=0;j<8;++j) lr[grp][m0+j] = racc[j];
  __syncthreads();
  if (t < MM){
    float s=0.f;
    #pragma unroll
    for (int g=0; g<16; ++g) s += lr[g][t];
    rpart[((size_t)b*SS + blockIdx.x)*MM + t] = s;
  }
}

// ---------------- Kernel B: controller + heads (one block per batch) -------
__global__ __launch_bounds__(1024) void kB(
    const float* __restrict__ xwx, int tstep,
    const float* __restrict__ Wr,
    const float* __restrict__ rWk, const float* __restrict__ rbk,
    const float* __restrict__ rWbeta, const float* __restrict__ rWg,
    const float* __restrict__ rWs, const float* __restrict__ rWgam,
    const float* __restrict__ wWk, const float* __restrict__ wbk,
    const float* __restrict__ wWbeta, const float* __restrict__ wWg,
    const float* __restrict__ wWs, const float* __restrict__ wWgam,
    const float* __restrict__ wWe, const float* __restrict__ wWa,
    const float* __restrict__ rpart,
    float* __restrict__ hG, float* __restrict__ krG, float* __restrict__ kwG,
    float* __restrict__ eG, float* __restrict__ aG, float* __restrict__ scal,
    float* __restrict__ outG)
{
  const int b = blockIdx.x, t = threadIdx.x;
  __shared__ float rs[MM], hs[HH], ks[2*MM], sd[14], hd[8][128];
  if (t < MM){
    float s=0.f;
    #pragma unroll
    for (int i=0;i<SS;++i) s += rpart[((size_t)b*SS+i)*MM + t];
    rs[t]=s;
  }
  __syncthreads();
  if (t < HH){
    float acc = xwx[((size_t)b*TT + tstep)*HH + t];
    #pragma unroll 4
    for (int m=0;m<MM;++m) acc += rs[m]*Wr[(size_t)m*HH + t];
    float hv = tanhf(acc);
    hs[t]=hv; hG[(size_t)b*HH+t]=hv;
    if (tstep == TT-1) outG[(size_t)b*HH+t]=hv;
  }
  __syncthreads();
  {
    const int q = t >> 7, m = t & 127;
    const int head = q & 3, jh = q >> 2;
    const float* W = (head==0)? rWk : (head==1)? wWk : (head==2)? wWe : wWa;
    float acc = 0.f;
    const int j0 = jh*256;
    #pragma unroll 4
    for (int j=j0; j<j0+256; ++j) acc += hs[j]*W[(size_t)j*MM + m];
    hd[q][m] = acc;
  }
  __syncthreads();
  if (t < 512){
    const int q = t >> 7, m = t & 127;
    float acc = hd[q][m] + hd[q+4][m];
    if (q==0){ float v=tanhf(acc + rbk[m]); ks[m]=v;    krG[b*MM+m]=v; }
    else if (q==1){ float v=tanhf(acc + wbk[m]); ks[MM+m]=v; kwG[b*MM+m]=v; }
    else if (q==2){ eG[b*MM+m]=sigmoidf_(acc); }
    else          { aG[b*MM+m]=tanhf(acc); }
  }
  __syncthreads();
  {
    const int wv = t>>6, ln = t&63;
    if (wv < 14){
      const int jj = wv;
      float acc=0.f;
      if (jj==6 || jj==13){
        const int o = (jj==6)? 0 : MM;
        const float v1=ks[o+ln], v2=ks[o+64+ln];
        acc = v1*v1 + v2*v2;
      } else {
        const int j2 = (jj<7)? jj : jj-7;
        const bool rd = (jj<7);
        const float* W; int C, c;
        switch (j2){
          case 0: W = rd? rWbeta : wWbeta; C=1; c=0; break;
          case 1: W = rd? rWg   : wWg;    C=1; c=0; break;
          case 2: W = rd? rWgam : wWgam;  C=1; c=0; break;
          default: W = rd? rWs  : wWs;    C=3; c=j2-3; break;
        }
        for (int j=ln; j<HH; j+=64) acc += hs[j]*W[j*C + c];
      }
      #pragma unroll
      for (int msk=1; msk<64; msk<<=1) acc += __shfl_xor(acc, msk);
      if (ln==0) sd[jj]=acc;
    }
  }
  __syncthreads();
  if (t==0){
    float* sc = scal + b*16;
    sc[0] = softplusf_(sd[0]);
    sc[1] = sigmoidf_(sd[1]);
    sc[2] = 1.f + softplusf_(sd[2]);
    {
      float mx = fmaxf(sd[3], fmaxf(sd[4], sd[5]));
      float e0=expf(sd[3]-mx), e1=expf(sd[4]-mx), e2=expf(sd[5]-mx);
      float inv=1.f/(e0+e1+e2);
      sc[3]=e0*inv; sc[4]=e1*inv; sc[5]=e2*inv;
    }
    sc[6] = sqrtf(sd[6]);
    sc[8]  = softplusf_(sd[7]);
    sc[9]  = sigmoidf_(sd[8]);
    sc[10] = 1.f + softplusf_(sd[9]);
    {
      float mx = fmaxf(sd[10], fmaxf(sd[11], sd[12]));
      float e0=expf(sd[10]-mx), e1=expf(sd[11]-mx), e2=expf(sd[12]-mx);
      float inv=1.f/(e0+e1+e2);
      sc[11]=e0*inv; sc[12]=e1*inv; sc[13]=e2*inv;
    }
    sc[14] = sqrtf(sd[13]);
  }
}

// ---------------- Kernel C: content dots for both heads --------------------
__global__ __launch_bounds__(256) void kC(
    const uint4* __restrict__ mem,
    const float* __restrict__ krG, const float* __restrict__ kwG,
    float* __restrict__ dotrG, float* __restrict__ dotwG)
{
  const int b = blockIdx.y;
  const int n0 = blockIdx.x * ROWS;
  const int t = threadIdx.x, grp=t>>4, lane=t&15;
  const int m0 = lane*8;
  float krv[8], kwv[8];
  {
    const float4 k0 = *(const float4*)(krG + b*MM + m0);
    const float4 k1 = *(const float4*)(krG + b*MM + m0 + 4);
    const float4 w0 = *(const float4*)(kwG + b*MM + m0);
    const float4 w1 = *(const float4*)(kwG + b*MM + m0 + 4);
    krv[0]=k0.x; krv[1]=k0.y; krv[2]=k0.z; krv[3]=k0.w;
    krv[4]=k1.x; krv[5]=k1.y; krv[6]=k1.z; krv[7]=k1.w;
    kwv[0]=w0.x; kwv[1]=w0.y; kwv[2]=w0.z; kwv[3]=w0.w;
    kwv[4]=w1.x; kwv[5]=w1.y; kwv[6]=w1.z; kwv[7]=w1.w;
  }
  const size_t base4 = ((size_t)b*NN + n0)*(MM/8) + (size_t)grp*(MM/8) + lane;
  uint4 q = mem[base4];
  #pragma unroll
  for (int rr=0; rr<8; ++rr){
    uint4 qn;
    if (rr<7) qn = mem[base4 + (size_t)(rr+1)*16*(MM/8)];
    const int n = n0 + rr*16 + grp;
    float v[8];
    unpack2(q.x, v[0], v[1]); unpack2(q.y, v[2], v[3]);
    unpack2(q.z, v[4], v[5]); unpack2(q.w, v[6], v[7]);
    float dr=0.f, dw=0.f;
    #pragma unroll
    for (int j=0;j<8;++j){ dr += v[j]*krv[j]; dw += v[j]*kwv[j]; }
    #pragma unroll
    for (int msk=1; msk<16; msk<<=1){
      dr += __shfl_xor(dr, msk);
      dw += __shfl_xor(dw, msk);
    }
    if (lane==0){ dotrG[b*NN+n]=dr; dotwG[b*NN+n]=dw; }
    q = qn;
  }
}

// ---------------- Kernel D: softmax + interpolate + shift + sharpen --------
__device__ __forceinline__ float blockSum256(float v, volatile float* sc){
  #pragma unroll
  for (int m=1;m<64;m<<=1) v += __shfl_xor(v,m);
  __syncthreads();
  if ((threadIdx.x&63)==0) sc[threadIdx.x>>6]=v;
  __syncthreads();
  return sc[0]+sc[1]+sc[2]+sc[3];
}
__device__ __forceinline__ float blockMax256(float v, volatile float* sc){
  #pragma unroll
  for (int m=1;m<64;m<<=1) v = fmaxf(v, __shfl_xor(v,m));
  __syncthreads();
  if ((threadIdx.x&63)==0) sc[threadIdx.x>>6]=v;
  __syncthreads();
  return fmaxf(fmaxf(sc[0],sc[1]), fmaxf(sc[2],sc[3]));
}

__global__ __launch_bounds__(256) void kD(
    const float* __restrict__ dotrG, const float* __restrict__ dotwG,
    const float* __restrict__ mnormG, const float* __restrict__ scal,
    float* __restrict__ wrG, float* __restrict__ wwG)
{
  const int b = blockIdx.x, head = blockIdx.y, t = threadIdx.x;
  __shared__ float wg[NN];
  __shared__ float sc[4];
  const float* dot = head? dotwG : dotrG;
  float* wv = head? wwG : wrG;
  const float* sb = scal + b*16 + head*8;
  const float beta=sb[0], g=sb[1], gamma=sb[2];
  const float s0=sb[3], s1=sb[4], s2=sb[5], knorm=sb[6];
  float sim[16]; float mx = -1e30f;
  #pragma unroll
  for (int i=0;i<16;++i){
    const int n = i*256 + t;
    const float d  = dot[(size_t)b*NN+n];
    const float mn = mnormG[(size_t)b*NN+n];
    sim[i] = beta*d/(mn*knorm + EPSF);
    mx = fmaxf(mx, sim[i]);
  }
  mx = blockMax256(mx, sc);
  float sum=0.f;
  #pragma unroll
  for (int i=0;i<16;++i){ sim[i]=__expf(sim[i]-mx); sum += sim[i]; }
  sum = blockSum256(sum, sc);
  const float inv = 1.f/sum;
  #pragma unroll
  for (int i=0;i<16;++i){
    const int n = i*256 + t;
    wg[n] = g*sim[i]*inv + (1.f-g)*wv[(size_t)b*NN+n];
  }
  __syncthreads();
  float wp[16]; float ps=0.f;
  #pragma unroll
  for (int i=0;i<16;++i){
    const int n = i*256 + t;
    const float wt = s0*wg[(n+1)&(NN-1)] + s1*wg[n] + s2*wg[(n-1)&(NN-1)];
    wp[i] = __powf(wt + EPSF, gamma);
    ps += wp[i];
  }
  ps = blockSum256(ps, sc);
  const float ip = 1.f/ps;
  #pragma unroll
  for (int i=0;i<16;++i){
    const int n = i*256 + t;
    wv[(size_t)b*NN+n] = wp[i]*ip;
  }
}

// ---------------- init -----------------------------------------------------
__global__ void kInit(float* wr, float* ww, float* h, float* e, float* a){
  const int i = blockIdx.x*blockDim.x + threadIdx.x;
  if (i < BB*NN){ const float v = (i==0)? 1.f : 0.f; wr[i]=v; ww[i]=v; }
  if (i < BB*HH) h[i]=0.f;
  if (i < BB*MM){ e[i]=0.5f; a[i]=0.f; }
}

extern "C" void kernel_launch(void* const* d_in, const int* in_sizes, int n_in,
                              void* d_out, int out_size, void* d_ws, size_t ws_size,
                              hipStream_t stream)
{
  const float* x     = (const float*)d_in[0];
  const float* mem0  = (const float*)d_in[1];
  const float* Wx    = (const float*)d_in[2];
  const float* Wr    = (const float*)d_in[3];
  const float* bC    = (const float*)d_in[4];
  const float* rWk   = (const float*)d_in[5];
  const float* rbk   = (const float*)d_in[6];
  const float* rWbeta= (const float*)d_in[7];
  const float* rWg   = (const float*)d_in[8];
  const float* rWs   = (const float*)d_in[9];
  const float* rWgam = (const float*)d_in[10];
  const float* wWk   = (const float*)d_in[11];
  const float* wbk   = (const float*)d_in[12];
  const float* wWbeta= (const float*)d_in[13];
  const float* wWg   = (const float*)d_in[14];
  const float* wWs   = (const float*)d_in[15];
  const float* wWgam = (const float*)d_in[16];
  const float* wWe   = (const float*)d_in[17];
  const float* wWa   = (const float*)d_in[18];

  float* ws = (float*)d_ws;
  size_t o = 0;
  uint4* mem   = (uint4*)(ws + o); o += (size_t)BB*NN*MM/2;  // bf16 = half the floats
  float* wr    = ws + o; o += (size_t)BB*NN;
  float* ww    = ws + o; o += (size_t)BB*NN;
  float* h     = ws + o; o += (size_t)BB*HH;
  float* rpart = ws + o; o += (size_t)BB*SS*MM;
  float* e     = ws + o; o += (size_t)BB*MM;
  float* a     = ws + o; o += (size_t)BB*MM;
  float* kr    = ws + o; o += (size_t)BB*MM;
  float* kw    = ws + o; o += (size_t)BB*MM;
  float* mnorm = ws + o; o += (size_t)BB*NN;
  float* dotr  = ws + o; o += (size_t)BB*NN;
  float* dotw  = ws + o; o += (size_t)BB*NN;
  float* scal  = ws + o; o += (size_t)BB*16;
  float* xwx   = ws + o; o += (size_t)BB*TT*HH;

  kCvt<<<(BB*NN*MM/8)/256, 256, 0, stream>>>(mem0, mem);
  kInit<<<(BB*NN+255)/256, 256, 0, stream>>>(wr, ww, h, e, a);
  kPre<<<BB*TT, 512, 0, stream>>>(x, Wx, bC, xwx);

  for (int t=0; t<TT; ++t){
    kA<<<dim3(SS,BB), 256, 0, stream>>>(e, a, wr, ww, mem, rpart, mnorm);
    kB<<<BB, 1024, 0, stream>>>(xwx, t, Wr,
                               rWk, rbk, rWbeta, rWg, rWs, rWgam,
                               wWk, wbk, wWbeta, wWg, wWs, wWgam, wWe, wWa,
                               rpart, h, kr, kw, e, a, scal, (float*)d_out);
    if (t < TT-1){
      kC<<<dim3(SS,BB), 256, 0, stream>>>(mem, kr, kw, dotr, dotw);
      kD<<<dim3(BB,2), 256, 0, stream>>>(dotr, dotw, mnorm, scal, wr, ww);
    }
  }
}